// Round 5
// baseline (827.732 us; speedup 1.0000x reference)
//
#include <hip/hip_runtime.h>
#include <hip/hip_bf16.h>

#define B_ 2
#define S_ 2048
#define E_ 2048
#define H_ 16
#define D_ 128
#define I_ 8192
#define T_ (B_*S_)

typedef __attribute__((ext_vector_type(8))) short bf16x8;      // 8 bf16 in 4 VGPRs
typedef __attribute__((ext_vector_type(8))) unsigned short us8;
typedef __attribute__((ext_vector_type(4))) float f32x4;

__device__ __forceinline__ unsigned short f2bf(float f) {
  union { float f; unsigned int u; } c; c.f = f;
  unsigned int u = c.u;
  unsigned int r = (u + 0x7fffu + ((u >> 16) & 1u)) >> 16;
  return (unsigned short)r;
}

__device__ __forceinline__ void gload16(const void* g, void* l) {
  __builtin_amdgcn_global_load_lds((const __attribute__((address_space(1))) void*)g,
                                   (__attribute__((address_space(3))) void*)l, 16, 0, 0);
}

// ---------------- weight fp32 (K,N) -> bf16 (N,K) transpose ----------------
__global__ void transpose_w(const float* __restrict__ in, unsigned short* __restrict__ out,
                            int K, int N) {
  __shared__ float tile[32][33];
  const int n0 = blockIdx.x * 32, k0 = blockIdx.y * 32;
  const int tx = threadIdx.x, ty = threadIdx.y;
#pragma unroll
  for (int j = 0; j < 4; ++j) {
    int k = k0 + ty + j * 8;
    tile[ty + j * 8][tx] = in[(size_t)k * N + n0 + tx];
  }
  __syncthreads();
#pragma unroll
  for (int j = 0; j < 4; ++j) {
    int n = n0 + ty + j * 8;
    out[(size_t)n * K + k0 + tx] = f2bf(tile[tx][ty + j * 8]);
  }
}

// ---------------- LayerNorm: fp32 (T,E) -> bf16 (T,E) ----------------
__global__ void ln_kernel(const float* __restrict__ x, const float* __restrict__ w,
                          const float* __restrict__ b, unsigned short* __restrict__ out) {
  const int row = blockIdx.x;
  const int tid = threadIdx.x;
  const int wid = tid >> 6, lane = tid & 63;
  const float4* xr = (const float4*)(x + (size_t)row * E_);
  float4 v0 = xr[tid * 2], v1 = xr[tid * 2 + 1];
  float s  = v0.x + v0.y + v0.z + v0.w + v1.x + v1.y + v1.z + v1.w;
  float sq = v0.x*v0.x + v0.y*v0.y + v0.z*v0.z + v0.w*v0.w
           + v1.x*v1.x + v1.y*v1.y + v1.z*v1.z + v1.w*v1.w;
#pragma unroll
  for (int off = 32; off > 0; off >>= 1) {
    s  += __shfl_xor(s, off);
    sq += __shfl_xor(sq, off);
  }
  __shared__ float red[8];
  if (lane == 0) { red[wid] = s; red[wid + 4] = sq; }
  __syncthreads();
  s  = red[0] + red[1] + red[2] + red[3];
  sq = red[4] + red[5] + red[6] + red[7];
  const float mu  = s * (1.0f / E_);
  const float var = sq * (1.0f / E_) - mu * mu;
  const float rstd = rsqrtf(var + 1e-5f);
  const float4* w4 = (const float4*)w + tid * 2;
  const float4* b4 = (const float4*)b + tid * 2;
  float4 w0 = w4[0], w1 = w4[1], bb0 = b4[0], bb1 = b4[1];
  us8 o;
  o[0] = f2bf((v0.x - mu) * rstd * w0.x + bb0.x);
  o[1] = f2bf((v0.y - mu) * rstd * w0.y + bb0.y);
  o[2] = f2bf((v0.z - mu) * rstd * w0.z + bb0.z);
  o[3] = f2bf((v0.w - mu) * rstd * w0.w + bb0.w);
  o[4] = f2bf((v1.x - mu) * rstd * w1.x + bb1.x);
  o[5] = f2bf((v1.y - mu) * rstd * w1.y + bb1.y);
  o[6] = f2bf((v1.z - mu) * rstd * w1.z + bb1.z);
  o[7] = f2bf((v1.w - mu) * rstd * w1.w + bb1.w);
  *(us8*)(&out[(size_t)row * E_ + tid * 8]) = o;
}

// ---------------- 256x256 8-phase GEMM: C(M,N) = A(M,K) @ Bt(N,K)^T ----------------
// 512 threads = 8 waves (2 Mrows x 4 Ncols), per-wave output 128x64.
// BK=64 as 2 k-halves of 32; LDS = 2 ops x 2 dbuf x 2 khalf x 16KB = 128 KB.
// Khalf layout: pair-packed [prow=row>>1][ (row&1)*32 + k ] with 16B-chunk XOR
// swizzle (chunk ^= prow&7) -> conflict-free b128 reads. Staged via
// global_load_lds with inverse-swizzled per-lane global source (linear dest).
// Counted vmcnt(4) at ends of ph1/ph3 (never 0 in steady state).
// EPI: 0 = store bf16, 1 = tanh-gelu bf16, 2 = +resid store fp32
template<int EPI>
__global__ __launch_bounds__(512, 2)
void gemm256(const unsigned short* __restrict__ A,
             const unsigned short* __restrict__ Bt,
             void* __restrict__ Cout,
             const float* __restrict__ resid,
             int M, int N, int K) {
  __shared__ __align__(16) unsigned short lds[65536];   // 128 KB
  const int gn = N >> 8;
  const int nwg = (M >> 8) * gn;
  const int cpx = nwg >> 3;                 // nwg % 8 == 0 for all our shapes
  const int bid = blockIdx.x;
  const int swz = (bid & 7) * cpx + (bid >> 3);
  const int bm = swz / gn, bn = swz % gn;
  const int tid = threadIdx.x;
  const int w = tid >> 6, lane = tid & 63;
  const int fr = lane & 15, kg = lane >> 4;
  const int wr = w >> 2, wc = w & 3;

  // ---- staging source mapping (inverse swizzle; round-trip verified) ----
  const int cc_s = (tid & 7) ^ ((tid >> 3) & 7);
  const int row_s = 2 * (tid >> 3) + (cc_s >> 2);      // + i*128 for issue 1
  const int ks_s = (cc_s & 3) * 8;                     // shorts within khalf
  const unsigned short* gA = A  + (size_t)(bm * 256 + row_s) * K + ks_s;
  const unsigned short* gB = Bt + (size_t)(bn * 256 + row_s) * K + ks_s;

  // ---- fragment read offset (within a khalf region, shorts) ----
  const int lread = (fr >> 1) * 64 + ((((fr & 1) * 4 + kg) ^ (fr >> 1)) * 8);

  auto STG = [&](const unsigned short* g, unsigned short* l) {
    gload16(g, l);
    gload16(g + (size_t)128 * K, l + 4096);
  };
  // region base (shorts): op{0=A,1=B}, dbuf c, khalf kh
#define REG_(op, c, kh) (((((op) * 2 + (c)) * 2 + (kh))) * 8192)

  f32x4 acc[8][4] = {};
  bf16x8 af[4], bq[4];

  auto LDA4 = [&](int c, int kh, int mh) {
    const unsigned short* p = &lds[REG_(0, c, kh) + (wr * 64 + mh * 32) * 64 + lread];
#pragma unroll
    for (int m = 0; m < 4; ++m) af[m] = *(const bf16x8*)(p + m * 512);
  };
  auto LDB4 = [&](int c, int kh) {
    const unsigned short* p = &lds[REG_(1, c, kh) + (wc * 32) * 64 + lread];
#pragma unroll
    for (int n = 0; n < 4; ++n) bq[n] = *(const bf16x8*)(p + n * 512);
  };
  auto MM16 = [&](int mh) {
    __builtin_amdgcn_s_setprio(1);
#pragma unroll
    for (int m = 0; m < 4; ++m)
#pragma unroll
      for (int n = 0; n < 4; ++n)
        acc[mh * 4 + m][n] =
            __builtin_amdgcn_mfma_f32_16x16x32_bf16(af[m], bq[n], acc[mh * 4 + m][n], 0, 0, 0);
    __builtin_amdgcn_s_setprio(0);
  };

  const int nk = K >> 6;
  // prologue: stage tile 0 -> buf 0, order A-kh0, B-kh0, A-kh1, B-kh1
  STG(gA,      &lds[REG_(0, 0, 0) + w * 512]);
  STG(gB,      &lds[REG_(1, 0, 0) + w * 512]);
  STG(gA + 32, &lds[REG_(0, 0, 1) + w * 512]);
  STG(gB + 32, &lds[REG_(1, 0, 1) + w * 512]);
  asm volatile("s_waitcnt vmcnt(4)" ::: "memory");   // kh0 pair landed
  __builtin_amdgcn_s_barrier();

  for (int kt = 0; kt < nk; ++kt) {
    const int c = kt & 1, d = c ^ 1;
    const bool pf = (kt + 1 < nk);
    const int knext = (kt + 1) * 64;
    // ---- ph0: mh0 x kh0 ----
    LDA4(c, 0, 0); LDB4(c, 0);
    if (pf) STG(gA + knext, &lds[REG_(0, d, 0) + w * 512]);
    __builtin_amdgcn_s_barrier();
    asm volatile("s_waitcnt lgkmcnt(0)" ::: "memory");
    __builtin_amdgcn_sched_barrier(0);
    MM16(0);
    __builtin_amdgcn_s_barrier();
    // ---- ph1: mh1 x kh0 (reuse bq) ----
    LDA4(c, 0, 1);
    if (pf) STG(gB + knext, &lds[REG_(1, d, 0) + w * 512]);
    __builtin_amdgcn_s_barrier();
    asm volatile("s_waitcnt lgkmcnt(0)" ::: "memory");
    __builtin_amdgcn_sched_barrier(0);
    MM16(1);
    if (pf) asm volatile("s_waitcnt vmcnt(4)" ::: "memory");  // this-tile kh1 landed
    else    asm volatile("s_waitcnt vmcnt(0)" ::: "memory");  // epilogue drain
    __builtin_amdgcn_s_barrier();
    // ---- ph2: mh0 x kh1 ----
    LDA4(c, 1, 0); LDB4(c, 1);
    if (pf) STG(gA + knext + 32, &lds[REG_(0, d, 1) + w * 512]);
    __builtin_amdgcn_s_barrier();
    asm volatile("s_waitcnt lgkmcnt(0)" ::: "memory");
    __builtin_amdgcn_sched_barrier(0);
    MM16(0);
    __builtin_amdgcn_s_barrier();
    // ---- ph3: mh1 x kh1 ----
    LDA4(c, 1, 1);
    if (pf) STG(gB + knext + 32, &lds[REG_(1, d, 1) + w * 512]);
    __builtin_amdgcn_s_barrier();
    asm volatile("s_waitcnt lgkmcnt(0)" ::: "memory");
    __builtin_amdgcn_sched_barrier(0);
    MM16(1);
    if (pf) asm volatile("s_waitcnt vmcnt(4)" ::: "memory");  // next-tile kh0 landed
    __builtin_amdgcn_s_barrier();
  }

  const int row0 = bm * 256 + wr * 128;
  const int col0 = bn * 256 + wc * 64;
#pragma unroll
  for (int m = 0; m < 8; ++m) {
#pragma unroll
    for (int n = 0; n < 4; ++n) {
#pragma unroll
      for (int r = 0; r < 4; ++r) {
        const int row = row0 + m * 16 + kg * 4 + r;
        const int col = col0 + n * 16 + fr;
        const size_t idx = (size_t)row * N + col;
        const float v = acc[m][n][r];
        if constexpr (EPI == 0) {
          ((unsigned short*)Cout)[idx] = f2bf(v);
        } else if constexpr (EPI == 1) {
          const float u = 0.7978845608028654f * (v + 0.044715f * v * v * v);
          const float gel = 0.5f * v * (1.0f + tanhf(u));
          ((unsigned short*)Cout)[idx] = f2bf(gel);
        } else {
          ((float*)Cout)[idx] = v + resid[idx];
        }
      }
    }
  }
#undef REG_
}

// ---------------- extract V^T: qkv (T,6144) -> vT (B,H,D,S) bf16 ----------------
__global__ void extract_vT(const unsigned short* __restrict__ qkv, unsigned short* __restrict__ vT) {
  __shared__ unsigned short tile[32][34];
  const int bh = blockIdx.z;               // b*H + h
  const int b = bh >> 4, h = bh & 15;
  const int s0 = blockIdx.y * 32, d0 = blockIdx.x * 32;
  const int tx = threadIdx.x, ty = threadIdx.y;
#pragma unroll
  for (int j = 0; j < 4; ++j) {
    int s = s0 + ty + j * 8;
    tile[ty + j * 8][tx] = qkv[(size_t)(b * S_ + s) * 6144 + 4096 + h * 128 + d0 + tx];
  }
  __syncthreads();
#pragma unroll
  for (int j = 0; j < 4; ++j) {
    int d = d0 + ty + j * 8;
    vT[((size_t)bh * 128 + d) * 2048 + s0 + tx] = tile[tx][ty + j * 8];
  }
}

// ---------------- causal flash attention ----------------
// grid (S/64, B*H), block 256 (4 waves).  Wave w: q-rows [qt*64+16w, +16).
__global__ __launch_bounds__(256, 2)
void attn_kernel(const unsigned short* __restrict__ qkv,
                 const unsigned short* __restrict__ vT,
                 unsigned short* __restrict__ outp) {
  __shared__ __align__(16) unsigned short Ks[64 * 128];    // 16 KB, swizzled
  __shared__ __align__(16) unsigned short Vts[128 * 64];   // 16 KB, swizzled
  __shared__ __align__(16) unsigned short Ps[4 * 16 * 40]; // 5 KB, per-wave P tile
  const int qt = blockIdx.x;
  const int bh = blockIdx.y;
  const int b = bh >> 4, h = bh & 15;
  const int tid = threadIdx.x, wid = tid >> 6, lane = tid & 63;
  const int fr = lane & 15, g = lane >> 4;

  const unsigned short* qptr = qkv + (size_t)(b * S_ + qt * 64 + wid * 16 + fr) * 6144 + h * 128;
  bf16x8 qf[4];
#pragma unroll
  for (int dc = 0; dc < 4; ++dc) qf[dc] = *(const bf16x8*)(qptr + dc * 32 + g * 8);

  float m0[4], l0[4];
#pragma unroll
  for (int r = 0; r < 4; ++r) { m0[r] = -1e30f; l0[r] = 0.0f; }
  f32x4 acc[8] = {};

  const unsigned short* kbase = qkv + (size_t)(b * S_) * 6144 + 2048 + h * 128;
  const unsigned short* vbase = vT + (size_t)bh * 128 * 2048;
  unsigned short* Pw = &Ps[wid * 640];
  const float scale = 0.08838834764831845f;

  us8 kreg[4], vreg[4];
#pragma unroll
  for (int j = 0; j < 4; ++j) {
    const int cc = tid + 256 * j;
    kreg[j] = *(const us8*)(kbase + (size_t)(cc >> 4) * 6144 + (cc & 15) * 8);
    vreg[j] = *(const us8*)(vbase + (size_t)(cc >> 3) * 2048 + (cc & 7) * 8);
  }

  for (int kt = 0; kt <= qt; ++kt) {
    __syncthreads();
#pragma unroll
    for (int j = 0; j < 4; ++j) {
      const int cc = tid + 256 * j;
      const int krow = cc >> 4, kcp = cc & 15;
      *(us8*)(&Ks[krow * 128 + ((kcp * 8) ^ ((krow & 7) << 3))]) = kreg[j];
      const int drow = cc >> 3, vcp = cc & 7;
      *(us8*)(&Vts[drow * 64 + ((vcp * 8) ^ ((drow & 7) << 3))]) = vreg[j];
    }
    if (kt < qt) {
#pragma unroll
      for (int j = 0; j < 4; ++j) {
        const int cc = tid + 256 * j;
        kreg[j] = *(const us8*)(kbase + (size_t)((kt + 1) * 64 + (cc >> 4)) * 6144 + (cc & 15) * 8);
        vreg[j] = *(const us8*)(vbase + (size_t)(cc >> 3) * 2048 + (kt + 1) * 64 + (cc & 7) * 8);
      }
    }
    __syncthreads();

    f32x4 sc[4] = {};
    __builtin_amdgcn_s_setprio(1);
#pragma unroll
    for (int dc = 0; dc < 4; ++dc) {
#pragma unroll
      for (int sub = 0; sub < 4; ++sub) {
        const int row = sub * 16 + fr;
        bf16x8 kf = *(const bf16x8*)(&Ks[row * 128 + ((dc * 32 + g * 8) ^ ((row & 7) << 3))]);
        sc[sub] = __builtin_amdgcn_mfma_f32_16x16x32_bf16(qf[dc], kf, sc[sub], 0, 0, 0);
      }
    }
    __builtin_amdgcn_s_setprio(0);

    float p[4][4];
    const bool diag = (kt == qt);
#pragma unroll
    for (int sub = 0; sub < 4; ++sub) {
#pragma unroll
      for (int r = 0; r < 4; ++r) {
        float v = sc[sub][r] * scale;
        if (diag && (sub * 16 + fr > wid * 16 + g * 4 + r)) v = -1e30f;
        p[sub][r] = v;
      }
    }
    float corr[4];
#pragma unroll
    for (int r = 0; r < 4; ++r) {
      float mx = fmaxf(fmaxf(p[0][r], p[1][r]), fmaxf(p[2][r], p[3][r]));
#pragma unroll
      for (int off = 1; off < 16; off <<= 1) mx = fmaxf(mx, __shfl_xor(mx, off));
      const float mn = fmaxf(m0[r], mx);
      corr[r] = __expf(m0[r] - mn);
      m0[r] = mn;
      float rs = 0.0f;
#pragma unroll
      for (int sub = 0; sub < 4; ++sub) { p[sub][r] = __expf(p[sub][r] - mn); rs += p[sub][r]; }
#pragma unroll
      for (int off = 1; off < 16; off <<= 1) rs += __shfl_xor(rs, off);
      l0[r] = l0[r] * corr[r] + rs;
    }
#pragma unroll
    for (int dt = 0; dt < 8; ++dt)
#pragma unroll
      for (int r = 0; r < 4; ++r) acc[dt][r] *= corr[r];

#pragma unroll
    for (int half = 0; half < 2; ++half) {
#pragma unroll
      for (int s2 = 0; s2 < 2; ++s2)
#pragma unroll
        for (int r = 0; r < 4; ++r)
          Pw[(g * 4 + r) * 40 + s2 * 16 + fr] = f2bf(p[half * 2 + s2][r]);
      bf16x8 pf = *(const bf16x8*)(&Pw[fr * 40 + g * 8]);
      __builtin_amdgcn_s_setprio(1);
#pragma unroll
      for (int dt = 0; dt < 8; ++dt) {
        const int row = dt * 16 + fr;
        bf16x8 vf = *(const bf16x8*)(&Vts[row * 64 + ((half * 32 + g * 8) ^ ((row & 7) << 3))]);
        acc[dt] = __builtin_amdgcn_mfma_f32_16x16x32_bf16(pf, vf, acc[dt], 0, 0, 0);
      }
      __builtin_amdgcn_s_setprio(0);
    }
  }

  float inv[4];
#pragma unroll
  for (int r = 0; r < 4; ++r) inv[r] = 1.0f / l0[r];
#pragma unroll
  for (int dt = 0; dt < 8; ++dt)
#pragma unroll
    for (int r = 0; r < 4; ++r) {
      const size_t row = (size_t)(b * S_ + qt * 64 + wid * 16 + g * 4 + r);
      outp[row * E_ + h * 128 + dt * 16 + fr] = f2bf(acc[dt][r] * inv[r]);
    }
}

// ---------------- launcher ----------------
extern "C" void kernel_launch(void* const* d_in, const int* in_sizes, int n_in,
                              void* d_out, int out_size, void* d_ws, size_t ws_size,
                              hipStream_t stream) {
  (void)in_sizes; (void)n_in; (void)out_size; (void)ws_size;
  const float* x    = (const float*)d_in[0];
  const float* ln1w = (const float*)d_in[1];
  const float* ln1b = (const float*)d_in[2];
  const float* Wqkv = (const float*)d_in[3];
  const float* Wo   = (const float*)d_in[4];
  const float* ln2w = (const float*)d_in[5];
  const float* ln2b = (const float*)d_in[6];
  const float* W1   = (const float*)d_in[7];
  const float* W2   = (const float*)d_in[8];
  float* out = (float*)d_out;
  char* ws = (char*)d_ws;

  // workspace layout (bytes)
  unsigned short* WqkvT = (unsigned short*)(ws + 0);            // 25,165,824
  unsigned short* WoT   = (unsigned short*)(ws + 25165824);     //  8,388,608
  unsigned short* W1T   = (unsigned short*)(ws + 33554432);     // 33,554,432
  unsigned short* W2T   = (unsigned short*)(ws + 67108864);     // 33,554,432
  unsigned short* qkvb  = (unsigned short*)(ws + 100663296);    // 50,331,648
  unsigned short* vTb   = (unsigned short*)(ws + 150994944);    // 16,777,216
  unsigned short* gbuf  = (unsigned short*)(ws + 100663296);    // 67,108,864 (reuses qkv+vT)
  unsigned short* hbuf  = (unsigned short*)(ws + 167772160);    // 16,777,216 (h / attnout / h2)
  float*          x1    = (float*)         (ws + 184549376);    // 33,554,432

  const dim3 tb(32, 8);
  hipLaunchKernelGGL(transpose_w, dim3(6144 / 32, 2048 / 32), tb, 0, stream, Wqkv, WqkvT, 2048, 6144);
  hipLaunchKernelGGL(transpose_w, dim3(2048 / 32, 2048 / 32), tb, 0, stream, Wo,   WoT,   2048, 2048);
  hipLaunchKernelGGL(transpose_w, dim3(8192 / 32, 2048 / 32), tb, 0, stream, W1,   W1T,   2048, 8192);
  hipLaunchKernelGGL(transpose_w, dim3(2048 / 32, 8192 / 32), tb, 0, stream, W2,   W2T,   8192, 2048);

  hipLaunchKernelGGL(ln_kernel, dim3(T_), dim3(256), 0, stream, x, ln1w, ln1b, hbuf);
  hipLaunchKernelGGL((gemm256<0>), dim3(16 * 24), dim3(512), 0, stream,
                     hbuf, WqkvT, (void*)qkvb, (const float*)nullptr, T_, 6144, 2048);
  hipLaunchKernelGGL(extract_vT, dim3(4, 64, 32), tb, 0, stream, qkvb, vTb);
  hipLaunchKernelGGL(attn_kernel, dim3(S_ / 64, B_ * H_), dim3(256), 0, stream, qkvb, vTb, hbuf);
  hipLaunchKernelGGL((gemm256<2>), dim3(16 * 8), dim3(512), 0, stream,
                     hbuf, WoT, (void*)x1, x, T_, 2048, 2048);
  hipLaunchKernelGGL(ln_kernel, dim3(T_), dim3(256), 0, stream, x1, ln2w, ln2b, hbuf);
  hipLaunchKernelGGL((gemm256<1>), dim3(16 * 32), dim3(512), 0, stream,
                     hbuf, W1T, (void*)gbuf, (const float*)nullptr, T_, 8192, 2048);
  hipLaunchKernelGGL((gemm256<2>), dim3(16 * 8), dim3(512), 0, stream,
                     gbuf, W2T, (void*)out, x1, T_, 2048, 8192);
}

// Round 6
// 825.801 us; speedup vs baseline: 1.0023x; 1.0023x over previous
//
#include <hip/hip_runtime.h>
#include <hip/hip_bf16.h>

#define B_ 2
#define S_ 2048
#define E_ 2048
#define H_ 16
#define D_ 128
#define I_ 8192
#define T_ (B_*S_)

typedef __attribute__((ext_vector_type(8))) short bf16x8;      // 8 bf16 in 4 VGPRs
typedef __attribute__((ext_vector_type(8))) unsigned short us8;
typedef __attribute__((ext_vector_type(4))) float f32x4;

__device__ __forceinline__ unsigned short f2bf(float f) {
  union { float f; unsigned int u; } c; c.f = f;
  unsigned int u = c.u;
  unsigned int r = (u + 0x7fffu + ((u >> 16) & 1u)) >> 16;
  return (unsigned short)r;
}

__device__ __forceinline__ void gload16(const void* g, void* l) {
  __builtin_amdgcn_global_load_lds((const __attribute__((address_space(1))) void*)g,
                                   (__attribute__((address_space(3))) void*)l, 16, 0, 0);
}

// ---------------- weight fp32 (K,N) -> bf16 (N,K) transpose ----------------
__global__ void transpose_w(const float* __restrict__ in, unsigned short* __restrict__ out,
                            int K, int N) {
  __shared__ float tile[32][33];
  const int n0 = blockIdx.x * 32, k0 = blockIdx.y * 32;
  const int tx = threadIdx.x, ty = threadIdx.y;
#pragma unroll
  for (int j = 0; j < 4; ++j) {
    int k = k0 + ty + j * 8;
    tile[ty + j * 8][tx] = in[(size_t)k * N + n0 + tx];
  }
  __syncthreads();
#pragma unroll
  for (int j = 0; j < 4; ++j) {
    int n = n0 + ty + j * 8;
    out[(size_t)n * K + k0 + tx] = f2bf(tile[tx][ty + j * 8]);
  }
}

// ---------------- LayerNorm: fp32 (T,E) -> bf16 (T,E) ----------------
__global__ void ln_kernel(const float* __restrict__ x, const float* __restrict__ w,
                          const float* __restrict__ b, unsigned short* __restrict__ out) {
  const int row = blockIdx.x;
  const int tid = threadIdx.x;
  const int wid = tid >> 6, lane = tid & 63;
  const float4* xr = (const float4*)(x + (size_t)row * E_);
  float4 v0 = xr[tid * 2], v1 = xr[tid * 2 + 1];
  float s  = v0.x + v0.y + v0.z + v0.w + v1.x + v1.y + v1.z + v1.w;
  float sq = v0.x*v0.x + v0.y*v0.y + v0.z*v0.z + v0.w*v0.w
           + v1.x*v1.x + v1.y*v1.y + v1.z*v1.z + v1.w*v1.w;
#pragma unroll
  for (int off = 32; off > 0; off >>= 1) {
    s  += __shfl_xor(s, off);
    sq += __shfl_xor(sq, off);
  }
  __shared__ float red[8];
  if (lane == 0) { red[wid] = s; red[wid + 4] = sq; }
  __syncthreads();
  s  = red[0] + red[1] + red[2] + red[3];
  sq = red[4] + red[5] + red[6] + red[7];
  const float mu  = s * (1.0f / E_);
  const float var = sq * (1.0f / E_) - mu * mu;
  const float rstd = rsqrtf(var + 1e-5f);
  const float4* w4 = (const float4*)w + tid * 2;
  const float4* b4 = (const float4*)b + tid * 2;
  float4 w0 = w4[0], w1 = w4[1], bb0 = b4[0], bb1 = b4[1];
  us8 o;
  o[0] = f2bf((v0.x - mu) * rstd * w0.x + bb0.x);
  o[1] = f2bf((v0.y - mu) * rstd * w0.y + bb0.y);
  o[2] = f2bf((v0.z - mu) * rstd * w0.z + bb0.z);
  o[3] = f2bf((v0.w - mu) * rstd * w0.w + bb0.w);
  o[4] = f2bf((v1.x - mu) * rstd * w1.x + bb1.x);
  o[5] = f2bf((v1.y - mu) * rstd * w1.y + bb1.y);
  o[6] = f2bf((v1.z - mu) * rstd * w1.z + bb1.z);
  o[7] = f2bf((v1.w - mu) * rstd * w1.w + bb1.w);
  *(us8*)(&out[(size_t)row * E_ + tid * 8]) = o;
}

// ---------------- 256x256 8-phase GEMM: C(M,N) = A(M,K) @ Bt(N,K)^T ----------------
// 512 threads = 8 waves (2 Mrows x 4 Ncols), per-wave output 128x64.
// BK=64 as 2 k-halves of 32; LDS = 2 ops x 2 dbuf x 2 khalf x 16KB = 128 KB.
// Khalf layout: pair-packed [prow=row>>1][ (row&1)*32 + k ] with 16B-chunk XOR
// swizzle (chunk ^= prow&7) -> conflict-free b128 reads (R5: conflicts == 0).
// Staged via global_load_lds, linear dest + inverse-swizzled global source.
// R5 lesson (m141 reproduction): sched_barrier(0) + "memory" clobbers on every
// waitcnt pinned the scheduler -> 545 TF. This round: NO sched_barrier, bare
// lgkmcnt(0) hints (compiler tracks ds_read->MFMA deps itself), "memory" only
// on the per-K-tile vmcnt publishes (gload_lds->ds_read dep is invisible to it).
// EPI: 0 = store bf16, 1 = tanh-gelu bf16, 2 = +resid store fp32
template<int EPI>
__global__ __launch_bounds__(512, 2)
void gemm256(const unsigned short* __restrict__ A,
             const unsigned short* __restrict__ Bt,
             void* __restrict__ Cout,
             const float* __restrict__ resid,
             int M, int N, int K) {
  __shared__ __align__(16) unsigned short lds[65536];   // 128 KB
  const int gn = N >> 8;
  const int nwg = (M >> 8) * gn;
  const int cpx = nwg >> 3;                 // nwg % 8 == 0 for all our shapes
  const int bid = blockIdx.x;
  const int swz = (bid & 7) * cpx + (bid >> 3);
  const int bm = swz / gn, bn = swz % gn;
  const int tid = threadIdx.x;
  const int w = tid >> 6, lane = tid & 63;
  const int fr = lane & 15, kg = lane >> 4;
  const int wr = w >> 2, wc = w & 3;

  // ---- staging source mapping (inverse swizzle; round-trip verified) ----
  const int cc_s = (tid & 7) ^ ((tid >> 3) & 7);
  const int row_s = 2 * (tid >> 3) + (cc_s >> 2);      // + 128 for issue 1
  const int ks_s = (cc_s & 3) * 8;                     // shorts within khalf
  const unsigned short* gA = A  + (size_t)(bm * 256 + row_s) * K + ks_s;
  const unsigned short* gB = Bt + (size_t)(bn * 256 + row_s) * K + ks_s;

  // ---- fragment read offset (within a khalf region, shorts) ----
  const int lread = (fr >> 1) * 64 + ((((fr & 1) * 4 + kg) ^ (fr >> 1)) * 8);

  auto STG = [&](const unsigned short* g, unsigned short* l) {
    gload16(g, l);
    gload16(g + (size_t)128 * K, l + 4096);
  };
  // region base (shorts): op{0=A,1=B}, dbuf c, khalf kh
#define REG_(op, c, kh) (((((op) * 2 + (c)) * 2 + (kh))) * 8192)

  f32x4 acc[8][4] = {};
  bf16x8 af[4], bq[4];

  auto LDA4 = [&](int c, int kh, int mh) {
    const unsigned short* p = &lds[REG_(0, c, kh) + (wr * 64 + mh * 32) * 64 + lread];
#pragma unroll
    for (int m = 0; m < 4; ++m) af[m] = *(const bf16x8*)(p + m * 512);
  };
  auto LDB4 = [&](int c, int kh) {
    const unsigned short* p = &lds[REG_(1, c, kh) + (wc * 32) * 64 + lread];
#pragma unroll
    for (int n = 0; n < 4; ++n) bq[n] = *(const bf16x8*)(p + n * 512);
  };
  auto MM16 = [&](int mh) {
    __builtin_amdgcn_s_setprio(1);
#pragma unroll
    for (int m = 0; m < 4; ++m)
#pragma unroll
      for (int n = 0; n < 4; ++n)
        acc[mh * 4 + m][n] =
            __builtin_amdgcn_mfma_f32_16x16x32_bf16(af[m], bq[n], acc[mh * 4 + m][n], 0, 0, 0);
    __builtin_amdgcn_s_setprio(0);
  };

  const int nk = K >> 6;
  // prologue: stage tile 0 -> buf 0, order A-kh0, B-kh0, A-kh1, B-kh1
  STG(gA,      &lds[REG_(0, 0, 0) + w * 512]);
  STG(gB,      &lds[REG_(1, 0, 0) + w * 512]);
  STG(gA + 32, &lds[REG_(0, 0, 1) + w * 512]);
  STG(gB + 32, &lds[REG_(1, 0, 1) + w * 512]);
  asm volatile("s_waitcnt vmcnt(4)" ::: "memory");   // kh0 pair landed
  __builtin_amdgcn_s_barrier();

  for (int kt = 0; kt < nk; ++kt) {
    const int c = kt & 1, d = c ^ 1;
    const bool pf = (kt + 1 < nk);
    const int knext = (kt + 1) * 64;
    // ---- ph0: mh0 x kh0 ----
    LDA4(c, 0, 0); LDB4(c, 0);
    if (pf) STG(gA + knext, &lds[REG_(0, d, 0) + w * 512]);
    __builtin_amdgcn_s_barrier();
    asm volatile("s_waitcnt lgkmcnt(0)");
    MM16(0);
    __builtin_amdgcn_s_barrier();
    // ---- ph1: mh1 x kh0 (reuse bq) ----
    LDA4(c, 0, 1);
    if (pf) STG(gB + knext, &lds[REG_(1, d, 0) + w * 512]);
    __builtin_amdgcn_s_barrier();
    asm volatile("s_waitcnt lgkmcnt(0)");
    MM16(1);
    if (pf) asm volatile("s_waitcnt vmcnt(4)" ::: "memory");  // this-tile kh1 landed
    else    asm volatile("s_waitcnt vmcnt(0)" ::: "memory");  // epilogue drain
    __builtin_amdgcn_s_barrier();
    // ---- ph2: mh0 x kh1 ----
    LDA4(c, 1, 0); LDB4(c, 1);
    if (pf) STG(gA + knext + 32, &lds[REG_(0, d, 1) + w * 512]);
    __builtin_amdgcn_s_barrier();
    asm volatile("s_waitcnt lgkmcnt(0)");
    MM16(0);
    __builtin_amdgcn_s_barrier();
    // ---- ph3: mh1 x kh1 ----
    LDA4(c, 1, 1);
    if (pf) STG(gB + knext + 32, &lds[REG_(1, d, 1) + w * 512]);
    __builtin_amdgcn_s_barrier();
    asm volatile("s_waitcnt lgkmcnt(0)");
    MM16(1);
    if (pf) asm volatile("s_waitcnt vmcnt(4)" ::: "memory");  // next-tile kh0 landed
    __builtin_amdgcn_s_barrier();
  }

  const int row0 = bm * 256 + wr * 128;
  const int col0 = bn * 256 + wc * 64;
#pragma unroll
  for (int m = 0; m < 8; ++m) {
#pragma unroll
    for (int n = 0; n < 4; ++n) {
#pragma unroll
      for (int r = 0; r < 4; ++r) {
        const int row = row0 + m * 16 + kg * 4 + r;
        const int col = col0 + n * 16 + fr;
        const size_t idx = (size_t)row * N + col;
        const float v = acc[m][n][r];
        if constexpr (EPI == 0) {
          ((unsigned short*)Cout)[idx] = f2bf(v);
        } else if constexpr (EPI == 1) {
          const float u = 0.7978845608028654f * (v + 0.044715f * v * v * v);
          const float gel = 0.5f * v * (1.0f + tanhf(u));
          ((unsigned short*)Cout)[idx] = f2bf(gel);
        } else {
          ((float*)Cout)[idx] = v + resid[idx];
        }
      }
    }
  }
#undef REG_
}

// ---------------- extract V^T: qkv (T,6144) -> vT (B,H,D,S) bf16 ----------------
__global__ void extract_vT(const unsigned short* __restrict__ qkv, unsigned short* __restrict__ vT) {
  __shared__ unsigned short tile[32][34];
  const int bh = blockIdx.z;               // b*H + h
  const int b = bh >> 4, h = bh & 15;
  const int s0 = blockIdx.y * 32, d0 = blockIdx.x * 32;
  const int tx = threadIdx.x, ty = threadIdx.y;
#pragma unroll
  for (int j = 0; j < 4; ++j) {
    int s = s0 + ty + j * 8;
    tile[ty + j * 8][tx] = qkv[(size_t)(b * S_ + s) * 6144 + 4096 + h * 128 + d0 + tx];
  }
  __syncthreads();
#pragma unroll
  for (int j = 0; j < 4; ++j) {
    int d = d0 + ty + j * 8;
    vT[((size_t)bh * 128 + d) * 2048 + s0 + tx] = tile[tx][ty + j * 8];
  }
}

// ---------------- causal flash attention ----------------
// grid (S/64, B*H), block 256 (4 waves).  Wave w: q-rows [qt*64+16w, +16).
__global__ __launch_bounds__(256, 2)
void attn_kernel(const unsigned short* __restrict__ qkv,
                 const unsigned short* __restrict__ vT,
                 unsigned short* __restrict__ outp) {
  __shared__ __align__(16) unsigned short Ks[64 * 128];    // 16 KB, swizzled
  __shared__ __align__(16) unsigned short Vts[128 * 64];   // 16 KB, swizzled
  __shared__ __align__(16) unsigned short Ps[4 * 16 * 40]; // 5 KB, per-wave P tile
  const int qt = blockIdx.x;
  const int bh = blockIdx.y;
  const int b = bh >> 4, h = bh & 15;
  const int tid = threadIdx.x, wid = tid >> 6, lane = tid & 63;
  const int fr = lane & 15, g = lane >> 4;

  const unsigned short* qptr = qkv + (size_t)(b * S_ + qt * 64 + wid * 16 + fr) * 6144 + h * 128;
  bf16x8 qf[4];
#pragma unroll
  for (int dc = 0; dc < 4; ++dc) qf[dc] = *(const bf16x8*)(qptr + dc * 32 + g * 8);

  float m0[4], l0[4];
#pragma unroll
  for (int r = 0; r < 4; ++r) { m0[r] = -1e30f; l0[r] = 0.0f; }
  f32x4 acc[8] = {};

  const unsigned short* kbase = qkv + (size_t)(b * S_) * 6144 + 2048 + h * 128;
  const unsigned short* vbase = vT + (size_t)bh * 128 * 2048;
  unsigned short* Pw = &Ps[wid * 640];
  const float scale = 0.08838834764831845f;

  us8 kreg[4], vreg[4];
#pragma unroll
  for (int j = 0; j < 4; ++j) {
    const int cc = tid + 256 * j;
    kreg[j] = *(const us8*)(kbase + (size_t)(cc >> 4) * 6144 + (cc & 15) * 8);
    vreg[j] = *(const us8*)(vbase + (size_t)(cc >> 3) * 2048 + (cc & 7) * 8);
  }

  for (int kt = 0; kt <= qt; ++kt) {
    __syncthreads();
#pragma unroll
    for (int j = 0; j < 4; ++j) {
      const int cc = tid + 256 * j;
      const int krow = cc >> 4, kcp = cc & 15;
      *(us8*)(&Ks[krow * 128 + ((kcp * 8) ^ ((krow & 7) << 3))]) = kreg[j];
      const int drow = cc >> 3, vcp = cc & 7;
      *(us8*)(&Vts[drow * 64 + ((vcp * 8) ^ ((drow & 7) << 3))]) = vreg[j];
    }
    if (kt < qt) {
#pragma unroll
      for (int j = 0; j < 4; ++j) {
        const int cc = tid + 256 * j;
        kreg[j] = *(const us8*)(kbase + (size_t)((kt + 1) * 64 + (cc >> 4)) * 6144 + (cc & 15) * 8);
        vreg[j] = *(const us8*)(vbase + (size_t)(cc >> 3) * 2048 + (kt + 1) * 64 + (cc & 7) * 8);
      }
    }
    __syncthreads();

    f32x4 sc[4] = {};
    __builtin_amdgcn_s_setprio(1);
#pragma unroll
    for (int dc = 0; dc < 4; ++dc) {
#pragma unroll
      for (int sub = 0; sub < 4; ++sub) {
        const int row = sub * 16 + fr;
        bf16x8 kf = *(const bf16x8*)(&Ks[row * 128 + ((dc * 32 + g * 8) ^ ((row & 7) << 3))]);
        sc[sub] = __builtin_amdgcn_mfma_f32_16x16x32_bf16(qf[dc], kf, sc[sub], 0, 0, 0);
      }
    }
    __builtin_amdgcn_s_setprio(0);

    float p[4][4];
    const bool diag = (kt == qt);
#pragma unroll
    for (int sub = 0; sub < 4; ++sub) {
#pragma unroll
      for (int r = 0; r < 4; ++r) {
        float v = sc[sub][r] * scale;
        if (diag && (sub * 16 + fr > wid * 16 + g * 4 + r)) v = -1e30f;
        p[sub][r] = v;
      }
    }
    float corr[4];
#pragma unroll
    for (int r = 0; r < 4; ++r) {
      float mx = fmaxf(fmaxf(p[0][r], p[1][r]), fmaxf(p[2][r], p[3][r]));
#pragma unroll
      for (int off = 1; off < 16; off <<= 1) mx = fmaxf(mx, __shfl_xor(mx, off));
      const float mn = fmaxf(m0[r], mx);
      corr[r] = __expf(m0[r] - mn);
      m0[r] = mn;
      float rs = 0.0f;
#pragma unroll
      for (int sub = 0; sub < 4; ++sub) { p[sub][r] = __expf(p[sub][r] - mn); rs += p[sub][r]; }
#pragma unroll
      for (int off = 1; off < 16; off <<= 1) rs += __shfl_xor(rs, off);
      l0[r] = l0[r] * corr[r] + rs;
    }
#pragma unroll
    for (int dt = 0; dt < 8; ++dt)
#pragma unroll
      for (int r = 0; r < 4; ++r) acc[dt][r] *= corr[r];

#pragma unroll
    for (int half = 0; half < 2; ++half) {
#pragma unroll
      for (int s2 = 0; s2 < 2; ++s2)
#pragma unroll
        for (int r = 0; r < 4; ++r)
          Pw[(g * 4 + r) * 40 + s2 * 16 + fr] = f2bf(p[half * 2 + s2][r]);
      bf16x8 pf = *(const bf16x8*)(&Pw[fr * 40 + g * 8]);
      __builtin_amdgcn_s_setprio(1);
#pragma unroll
      for (int dt = 0; dt < 8; ++dt) {
        const int row = dt * 16 + fr;
        bf16x8 vf = *(const bf16x8*)(&Vts[row * 64 + ((half * 32 + g * 8) ^ ((row & 7) << 3))]);
        acc[dt] = __builtin_amdgcn_mfma_f32_16x16x32_bf16(pf, vf, acc[dt], 0, 0, 0);
      }
      __builtin_amdgcn_s_setprio(0);
    }
  }

  float inv[4];
#pragma unroll
  for (int r = 0; r < 4; ++r) inv[r] = 1.0f / l0[r];
#pragma unroll
  for (int dt = 0; dt < 8; ++dt)
#pragma unroll
    for (int r = 0; r < 4; ++r) {
      const size_t row = (size_t)(b * S_ + qt * 64 + wid * 16 + g * 4 + r);
      outp[row * E_ + h * 128 + dt * 16 + fr] = f2bf(acc[dt][r] * inv[r]);
    }
}

// ---------------- launcher ----------------
extern "C" void kernel_launch(void* const* d_in, const int* in_sizes, int n_in,
                              void* d_out, int out_size, void* d_ws, size_t ws_size,
                              hipStream_t stream) {
  (void)in_sizes; (void)n_in; (void)out_size; (void)ws_size;
  const float* x    = (const float*)d_in[0];
  const float* ln1w = (const float*)d_in[1];
  const float* ln1b = (const float*)d_in[2];
  const float* Wqkv = (const float*)d_in[3];
  const float* Wo   = (const float*)d_in[4];
  const float* ln2w = (const float*)d_in[5];
  const float* ln2b = (const float*)d_in[6];
  const float* W1   = (const float*)d_in[7];
  const float* W2   = (const float*)d_in[8];
  float* out = (float*)d_out;
  char* ws = (char*)d_ws;

  // workspace layout (bytes)
  unsigned short* WqkvT = (unsigned short*)(ws + 0);            // 25,165,824
  unsigned short* WoT   = (unsigned short*)(ws + 25165824);     //  8,388,608
  unsigned short* W1T   = (unsigned short*)(ws + 33554432);     // 33,554,432
  unsigned short* W2T   = (unsigned short*)(ws + 67108864);     // 33,554,432
  unsigned short* qkvb  = (unsigned short*)(ws + 100663296);    // 50,331,648
  unsigned short* vTb   = (unsigned short*)(ws + 150994944);    // 16,777,216
  unsigned short* gbuf  = (unsigned short*)(ws + 100663296);    // 67,108,864 (reuses qkv+vT)
  unsigned short* hbuf  = (unsigned short*)(ws + 167772160);    // 16,777,216 (h / attnout / h2)
  float*          x1    = (float*)         (ws + 184549376);    // 33,554,432

  const dim3 tb(32, 8);
  hipLaunchKernelGGL(transpose_w, dim3(6144 / 32, 2048 / 32), tb, 0, stream, Wqkv, WqkvT, 2048, 6144);
  hipLaunchKernelGGL(transpose_w, dim3(2048 / 32, 2048 / 32), tb, 0, stream, Wo,   WoT,   2048, 2048);
  hipLaunchKernelGGL(transpose_w, dim3(8192 / 32, 2048 / 32), tb, 0, stream, W1,   W1T,   2048, 8192);
  hipLaunchKernelGGL(transpose_w, dim3(2048 / 32, 8192 / 32), tb, 0, stream, W2,   W2T,   8192, 2048);

  hipLaunchKernelGGL(ln_kernel, dim3(T_), dim3(256), 0, stream, x, ln1w, ln1b, hbuf);
  hipLaunchKernelGGL((gemm256<0>), dim3(16 * 24), dim3(512), 0, stream,
                     hbuf, WqkvT, (void*)qkvb, (const float*)nullptr, T_, 6144, 2048);
  hipLaunchKernelGGL(extract_vT, dim3(4, 64, 32), tb, 0, stream, qkvb, vTb);
  hipLaunchKernelGGL(attn_kernel, dim3(S_ / 64, B_ * H_), dim3(256), 0, stream, qkvb, vTb, hbuf);
  hipLaunchKernelGGL((gemm256<2>), dim3(16 * 8), dim3(512), 0, stream,
                     hbuf, WoT, (void*)x1, x, T_, 2048, 2048);
  hipLaunchKernelGGL(ln_kernel, dim3(T_), dim3(256), 0, stream, x1, ln2w, ln2b, hbuf);
  hipLaunchKernelGGL((gemm256<1>), dim3(16 * 32), dim3(512), 0, stream,
                     hbuf, W1T, (void*)gbuf, (const float*)nullptr, T_, 8192, 2048);
  hipLaunchKernelGGL((gemm256<2>), dim3(16 * 8), dim3(512), 0, stream,
                     gbuf, W2T, (void*)out, x1, T_, 2048, 8192);
}

// Round 7
// 766.281 us; speedup vs baseline: 1.0802x; 1.0777x over previous
//
#include <hip/hip_runtime.h>
#include <hip/hip_bf16.h>

#define B_ 2
#define S_ 2048
#define E_ 2048
#define H_ 16
#define D_ 128
#define I_ 8192
#define T_ (B_*S_)

typedef __attribute__((ext_vector_type(8))) short bf16x8;      // 8 bf16 in 4 VGPRs
typedef __attribute__((ext_vector_type(8))) unsigned short us8;
typedef __attribute__((ext_vector_type(4))) float f32x4;

__device__ __forceinline__ unsigned short f2bf(float f) {
  union { float f; unsigned int u; } c; c.f = f;
  unsigned int u = c.u;
  unsigned int r = (u + 0x7fffu + ((u >> 16) & 1u)) >> 16;
  return (unsigned short)r;
}

__device__ __forceinline__ void gload16(const void* g, void* l) {
  __builtin_amdgcn_global_load_lds((const __attribute__((address_space(1))) void*)g,
                                   (__attribute__((address_space(3))) void*)l, 16, 0, 0);
}

// ---------------- weight fp32 (K,N) -> bf16 (N,K) transpose ----------------
__global__ void transpose_w(const float* __restrict__ in, unsigned short* __restrict__ out,
                            int K, int N) {
  __shared__ float tile[32][33];
  const int n0 = blockIdx.x * 32, k0 = blockIdx.y * 32;
  const int tx = threadIdx.x, ty = threadIdx.y;
#pragma unroll
  for (int j = 0; j < 4; ++j) {
    int k = k0 + ty + j * 8;
    tile[ty + j * 8][tx] = in[(size_t)k * N + n0 + tx];
  }
  __syncthreads();
#pragma unroll
  for (int j = 0; j < 4; ++j) {
    int n = n0 + ty + j * 8;
    out[(size_t)n * K + k0 + tx] = f2bf(tile[tx][ty + j * 8]);
  }
}

// ---------------- LayerNorm: fp32 (T,E) -> bf16 (T,E) ----------------
__global__ void ln_kernel(const float* __restrict__ x, const float* __restrict__ w,
                          const float* __restrict__ b, unsigned short* __restrict__ out) {
  const int row = blockIdx.x;
  const int tid = threadIdx.x;
  const int wid = tid >> 6, lane = tid & 63;
  const float4* xr = (const float4*)(x + (size_t)row * E_);
  float4 v0 = xr[tid * 2], v1 = xr[tid * 2 + 1];
  float s  = v0.x + v0.y + v0.z + v0.w + v1.x + v1.y + v1.z + v1.w;
  float sq = v0.x*v0.x + v0.y*v0.y + v0.z*v0.z + v0.w*v0.w
           + v1.x*v1.x + v1.y*v1.y + v1.z*v1.z + v1.w*v1.w;
#pragma unroll
  for (int off = 32; off > 0; off >>= 1) {
    s  += __shfl_xor(s, off);
    sq += __shfl_xor(sq, off);
  }
  __shared__ float red[8];
  if (lane == 0) { red[wid] = s; red[wid + 4] = sq; }
  __syncthreads();
  s  = red[0] + red[1] + red[2] + red[3];
  sq = red[4] + red[5] + red[6] + red[7];
  const float mu  = s * (1.0f / E_);
  const float var = sq * (1.0f / E_) - mu * mu;
  const float rstd = rsqrtf(var + 1e-5f);
  const float4* w4 = (const float4*)w + tid * 2;
  const float4* b4 = (const float4*)b + tid * 2;
  float4 w0 = w4[0], w1 = w4[1], bb0 = b4[0], bb1 = b4[1];
  us8 o;
  o[0] = f2bf((v0.x - mu) * rstd * w0.x + bb0.x);
  o[1] = f2bf((v0.y - mu) * rstd * w0.y + bb0.y);
  o[2] = f2bf((v0.z - mu) * rstd * w0.z + bb0.z);
  o[3] = f2bf((v0.w - mu) * rstd * w0.w + bb0.w);
  o[4] = f2bf((v1.x - mu) * rstd * w1.x + bb1.x);
  o[5] = f2bf((v1.y - mu) * rstd * w1.y + bb1.y);
  o[6] = f2bf((v1.z - mu) * rstd * w1.z + bb1.z);
  o[7] = f2bf((v1.w - mu) * rstd * w1.w + bb1.w);
  *(us8*)(&out[(size_t)row * E_ + tid * 8]) = o;
}

// ---------------- m97 128x128 GEMM (known-good R4): C = A @ Bt^T ----------------
template<int EPI>
__global__ void gemm_bt(const unsigned short* __restrict__ A,
                        const unsigned short* __restrict__ Bt,
                        void* __restrict__ Cout,
                        const float* __restrict__ resid,
                        int M, int N, int K) {
  __shared__ __align__(16) unsigned short As[128 * 32];
  __shared__ __align__(16) unsigned short Bs[128 * 32];
  const int gn = N >> 7;
  const int nwg = (M >> 7) * gn;
  const int cpx = nwg >> 3;
  const int bid = blockIdx.x;
  const int swz = (bid & 7) * cpx + (bid >> 3);
  const int bm = swz / gn, bn = swz % gn;
  const int tid = threadIdx.x;
  const int wid = tid >> 6, lane = tid & 63;
  const int fr = lane & 15, kg = lane >> 4;
  const int wr = wid >> 1, wc = wid & 1;

  const int c0 = wid * 2;
  const unsigned short* gA = A  + (size_t)(bm * 128 + c0 * 16 + (lane >> 2)) * K + (lane & 3) * 8;
  const unsigned short* gB = Bt + (size_t)(bn * 128 + c0 * 16 + (lane >> 2)) * K + (lane & 3) * 8;
  unsigned short* lA = &As[c0 * 512];
  unsigned short* lB = &Bs[c0 * 512];

  const unsigned short* rA = &As[(wr * 64 + fr) * 32 + kg * 8];
  const unsigned short* rB = &Bs[(wc * 64 + fr) * 32 + kg * 8];

  f32x4 acc[4][4] = {};
  const int nk = K >> 5;
  for (int kt = 0; kt < nk; ++kt) {
    __syncthreads();
    gload16(gA,                 lA);
    gload16(gA + 16 * (size_t)K, lA + 512);
    gload16(gB,                 lB);
    gload16(gB + 16 * (size_t)K, lB + 512);
    gA += 32; gB += 32;
    __syncthreads();
    bf16x8 af[4], bfr[4];
#pragma unroll
    for (int m = 0; m < 4; ++m) af[m]  = *(const bf16x8*)(rA + m * 16 * 32);
#pragma unroll
    for (int n = 0; n < 4; ++n) bfr[n] = *(const bf16x8*)(rB + n * 16 * 32);
#pragma unroll
    for (int m = 0; m < 4; ++m)
#pragma unroll
      for (int n = 0; n < 4; ++n)
        acc[m][n] = __builtin_amdgcn_mfma_f32_16x16x32_bf16(af[m], bfr[n], acc[m][n], 0, 0, 0);
  }

  const int row0 = bm * 128 + wr * 64;
  const int col0 = bn * 128 + wc * 64;
#pragma unroll
  for (int m = 0; m < 4; ++m) {
#pragma unroll
    for (int n = 0; n < 4; ++n) {
#pragma unroll
      for (int r = 0; r < 4; ++r) {
        const int row = row0 + m * 16 + kg * 4 + r;
        const int col = col0 + n * 16 + fr;
        const size_t idx = (size_t)row * N + col;
        const float v = acc[m][n][r];
        if constexpr (EPI == 0) {
          ((unsigned short*)Cout)[idx] = f2bf(v);
        } else if constexpr (EPI == 1) {
          const float u = 0.7978845608028654f * (v + 0.044715f * v * v * v);
          const float gel = 0.5f * v * (1.0f + tanhf(u));
          ((unsigned short*)Cout)[idx] = f2bf(gel);
        } else {
          ((float*)Cout)[idx] = v + resid[idx];
        }
      }
    }
  }
}

// ---------------- 256x256 8-phase GEMM, asm-ds_read variant ----------------
// R6 diagnosis: compiler-inserted vmcnt drains before C++ ds_reads (LDS-DMA
// aliasing, runtime dbuf index) serialized every phase. Fix: inline-asm
// ds_read_b128 (invisible to the waitcnt pass) + rule-18 fence
// (lgkmcnt(0)+sched_barrier(0)) before each MFMA cluster; manual vmcnt(4)
// gates are now the only DMA->read fences. K-loop unrolled 2 tiles/iter so
// buffer indices are compile-time literals.
#define DSR(dst, addr, off) \
  asm volatile("ds_read_b128 %0, %1 offset:%c2" : "=v"(dst) : "v"(addr), "i"(off))
#define LDA4_(aad, kh, mh) \
  DSR(af[0], aad, (kh)*16384 + (mh)*4096 + 0);    \
  DSR(af[1], aad, (kh)*16384 + (mh)*4096 + 1024); \
  DSR(af[2], aad, (kh)*16384 + (mh)*4096 + 2048); \
  DSR(af[3], aad, (kh)*16384 + (mh)*4096 + 3072)
#define LDB4_(bbd, kh) \
  DSR(bq[0], bbd, (kh)*16384 + 0);    \
  DSR(bq[1], bbd, (kh)*16384 + 1024); \
  DSR(bq[2], bbd, (kh)*16384 + 2048); \
  DSR(bq[3], bbd, (kh)*16384 + 3072)
#define FENCE_ do { asm volatile("s_waitcnt lgkmcnt(0)"); \
                    __builtin_amdgcn_sched_barrier(0); } while (0)
#define REG_(op, c, kh) (((((op) * 2 + (c)) * 2 + (kh))) * 8192)

template<int EPI>
__global__ __launch_bounds__(512, 2)
void gemm256(const unsigned short* __restrict__ A,
             const unsigned short* __restrict__ Bt,
             void* __restrict__ Cout,
             const float* __restrict__ resid,
             int M, int N, int K) {
  __shared__ __align__(16) unsigned short lds[65536];   // 128 KB
  const int gn = N >> 8;
  const int nwg = (M >> 8) * gn;
  const int cpx = nwg >> 3;
  const int bid = blockIdx.x;
  const int swz = (bid & 7) * cpx + (bid >> 3);
  const int bm = swz / gn, bn = swz % gn;
  const int tid = threadIdx.x;
  const int w = tid >> 6, lane = tid & 63;
  const int fr = lane & 15, kg = lane >> 4;
  const int wr = w >> 2, wc = w & 3;

  // staging source (inverse of the pair-packed XOR swizzle; R5: conflicts==0)
  const int cc_s = (tid & 7) ^ ((tid >> 3) & 7);
  const int row_s = 2 * (tid >> 3) + (cc_s >> 2);
  const int ks_s = (cc_s & 3) * 8;
  const unsigned short* gA = A  + (size_t)(bm * 256 + row_s) * K + ks_s;
  const unsigned short* gB = Bt + (size_t)(bn * 256 + row_s) * K + ks_s;

  // fragment read offset (shorts) within a khalf region
  const int lread = (fr >> 1) * 64 + ((((fr & 1) * 4 + kg) ^ (fr >> 1)) * 8);
  // byte addresses for asm ds_read: A region op0, B region +65536
  const int aA0 = wr * 8192 + lread * 2;
  const int aA1 = 32768 + wr * 8192 + lread * 2;
  const int bB0 = 65536 + wc * 4096 + lread * 2;
  const int bB1 = 65536 + 32768 + wc * 4096 + lread * 2;

  auto STG = [&](const unsigned short* g, unsigned short* l) {
    gload16(g, l);
    gload16(g + (size_t)128 * K, l + 4096);
  };

  f32x4 acc[8][4] = {};
  bf16x8 af[4], bq[4];

  auto MM16 = [&](int mh) {
    __builtin_amdgcn_s_setprio(1);
#pragma unroll
    for (int m = 0; m < 4; ++m)
#pragma unroll
      for (int n = 0; n < 4; ++n)
        acc[mh * 4 + m][n] =
            __builtin_amdgcn_mfma_f32_16x16x32_bf16(af[m], bq[n], acc[mh * 4 + m][n], 0, 0, 0);
    __builtin_amdgcn_s_setprio(0);
  };

#define KTILE(AAD, BBD, DB, kt)  {                                        \
    const bool pf = (kt) + 1 < nk;                                        \
    const unsigned short* gAn = gA + (size_t)((kt) + 1) * 64;             \
    const unsigned short* gBn = gB + (size_t)((kt) + 1) * 64;             \
    LDA4_(AAD, 0, 0); LDB4_(BBD, 0);                                      \
    if (pf) STG(gAn, &lds[REG_(0, DB, 0) + w * 512]);                     \
    __builtin_amdgcn_s_barrier(); FENCE_;                                 \
    MM16(0);                                                              \
    __builtin_amdgcn_s_barrier();                                         \
    LDA4_(AAD, 0, 1);                                                     \
    if (pf) STG(gBn, &lds[REG_(1, DB, 0) + w * 512]);                     \
    __builtin_amdgcn_s_barrier(); FENCE_;                                 \
    MM16(1);                                                              \
    if (pf) { asm volatile("s_waitcnt vmcnt(4)" ::: "memory"); }          \
    else    { asm volatile("s_waitcnt vmcnt(0)" ::: "memory"); }          \
    __builtin_amdgcn_s_barrier();                                         \
    LDA4_(AAD, 1, 0); LDB4_(BBD, 1);                                      \
    if (pf) STG(gAn + 32, &lds[REG_(0, DB, 1) + w * 512]);                \
    __builtin_amdgcn_s_barrier(); FENCE_;                                 \
    MM16(0);                                                              \
    __builtin_amdgcn_s_barrier();                                         \
    LDA4_(AAD, 1, 1);                                                     \
    if (pf) STG(gBn + 32, &lds[REG_(1, DB, 1) + w * 512]);                \
    __builtin_amdgcn_s_barrier(); FENCE_;                                 \
    MM16(1);                                                              \
    if (pf) { asm volatile("s_waitcnt vmcnt(4)" ::: "memory"); }          \
    __builtin_amdgcn_s_barrier();                                         \
  }

  const int nk = K >> 6;
  // prologue: stage tile 0 -> buf 0
  STG(gA,      &lds[REG_(0, 0, 0) + w * 512]);
  STG(gB,      &lds[REG_(1, 0, 0) + w * 512]);
  STG(gA + 32, &lds[REG_(0, 0, 1) + w * 512]);
  STG(gB + 32, &lds[REG_(1, 0, 1) + w * 512]);
  asm volatile("s_waitcnt vmcnt(4)" ::: "memory");   // kh0 pair landed
  __builtin_amdgcn_s_barrier();

  for (int kt2 = 0; kt2 < (nk >> 1); ++kt2) {
    KTILE(aA0, bB0, 1, 2 * kt2);
    KTILE(aA1, bB1, 0, 2 * kt2 + 1);
  }
#undef KTILE

  const int row0 = bm * 256 + wr * 128;
  const int col0 = bn * 256 + wc * 64;
#pragma unroll
  for (int m = 0; m < 8; ++m) {
#pragma unroll
    for (int n = 0; n < 4; ++n) {
#pragma unroll
      for (int r = 0; r < 4; ++r) {
        const int row = row0 + m * 16 + kg * 4 + r;
        const int col = col0 + n * 16 + fr;
        const size_t idx = (size_t)row * N + col;
        const float v = acc[m][n][r];
        if constexpr (EPI == 0) {
          ((unsigned short*)Cout)[idx] = f2bf(v);
        } else if constexpr (EPI == 1) {
          const float u = 0.7978845608028654f * (v + 0.044715f * v * v * v);
          const float gel = 0.5f * v * (1.0f + tanhf(u));
          ((unsigned short*)Cout)[idx] = f2bf(gel);
        } else {
          ((float*)Cout)[idx] = v + resid[idx];
        }
      }
    }
  }
}

// ---------------- extract V^T: qkv (T,6144) -> vT (B,H,D,S) bf16 ----------------
__global__ void extract_vT(const unsigned short* __restrict__ qkv, unsigned short* __restrict__ vT) {
  __shared__ unsigned short tile[32][34];
  const int bh = blockIdx.z;               // b*H + h
  const int b = bh >> 4, h = bh & 15;
  const int s0 = blockIdx.y * 32, d0 = blockIdx.x * 32;
  const int tx = threadIdx.x, ty = threadIdx.y;
#pragma unroll
  for (int j = 0; j < 4; ++j) {
    int s = s0 + ty + j * 8;
    tile[ty + j * 8][tx] = qkv[(size_t)(b * S_ + s) * 6144 + 4096 + h * 128 + d0 + tx];
  }
  __syncthreads();
#pragma unroll
  for (int j = 0; j < 4; ++j) {
    int d = d0 + ty + j * 8;
    vT[((size_t)bh * 128 + d) * 2048 + s0 + tx] = tile[tx][ty + j * 8];
  }
}

// ---------------- causal flash attention ----------------
__global__ __launch_bounds__(256, 2)
void attn_kernel(const unsigned short* __restrict__ qkv,
                 const unsigned short* __restrict__ vT,
                 unsigned short* __restrict__ outp) {
  __shared__ __align__(16) unsigned short Ks[64 * 128];    // 16 KB, swizzled
  __shared__ __align__(16) unsigned short Vts[128 * 64];   // 16 KB, swizzled
  __shared__ __align__(16) unsigned short Ps[4 * 16 * 40]; // 5 KB, per-wave P tile
  const int qt = blockIdx.x;
  const int bh = blockIdx.y;
  const int b = bh >> 4, h = bh & 15;
  const int tid = threadIdx.x, wid = tid >> 6, lane = tid & 63;
  const int fr = lane & 15, g = lane >> 4;

  const unsigned short* qptr = qkv + (size_t)(b * S_ + qt * 64 + wid * 16 + fr) * 6144 + h * 128;
  bf16x8 qf[4];
#pragma unroll
  for (int dc = 0; dc < 4; ++dc) qf[dc] = *(const bf16x8*)(qptr + dc * 32 + g * 8);

  float m0[4], l0[4];
#pragma unroll
  for (int r = 0; r < 4; ++r) { m0[r] = -1e30f; l0[r] = 0.0f; }
  f32x4 acc[8] = {};

  const unsigned short* kbase = qkv + (size_t)(b * S_) * 6144 + 2048 + h * 128;
  const unsigned short* vbase = vT + (size_t)bh * 128 * 2048;
  unsigned short* Pw = &Ps[wid * 640];
  const float scale = 0.08838834764831845f;

  us8 kreg[4], vreg[4];
#pragma unroll
  for (int j = 0; j < 4; ++j) {
    const int cc = tid + 256 * j;
    kreg[j] = *(const us8*)(kbase + (size_t)(cc >> 4) * 6144 + (cc & 15) * 8);
    vreg[j] = *(const us8*)(vbase + (size_t)(cc >> 3) * 2048 + (cc & 7) * 8);
  }

  for (int kt = 0; kt <= qt; ++kt) {
    __syncthreads();
#pragma unroll
    for (int j = 0; j < 4; ++j) {
      const int cc = tid + 256 * j;
      const int krow = cc >> 4, kcp = cc & 15;
      *(us8*)(&Ks[krow * 128 + ((kcp * 8) ^ ((krow & 7) << 3))]) = kreg[j];
      const int drow = cc >> 3, vcp = cc & 7;
      *(us8*)(&Vts[drow * 64 + ((vcp * 8) ^ ((drow & 7) << 3))]) = vreg[j];
    }
    if (kt < qt) {
#pragma unroll
      for (int j = 0; j < 4; ++j) {
        const int cc = tid + 256 * j;
        kreg[j] = *(const us8*)(kbase + (size_t)((kt + 1) * 64 + (cc >> 4)) * 6144 + (cc & 15) * 8);
        vreg[j] = *(const us8*)(vbase + (size_t)(cc >> 3) * 2048 + (kt + 1) * 64 + (cc & 7) * 8);
      }
    }
    __syncthreads();

    f32x4 sc[4] = {};
    __builtin_amdgcn_s_setprio(1);
#pragma unroll
    for (int dc = 0; dc < 4; ++dc) {
#pragma unroll
      for (int sub = 0; sub < 4; ++sub) {
        const int row = sub * 16 + fr;
        bf16x8 kf = *(const bf16x8*)(&Ks[row * 128 + ((dc * 32 + g * 8) ^ ((row & 7) << 3))]);
        sc[sub] = __builtin_amdgcn_mfma_f32_16x16x32_bf16(qf[dc], kf, sc[sub], 0, 0, 0);
      }
    }
    __builtin_amdgcn_s_setprio(0);

    float p[4][4];
    const bool diag = (kt == qt);
#pragma unroll
    for (int sub = 0; sub < 4; ++sub) {
#pragma unroll
      for (int r = 0; r < 4; ++r) {
        float v = sc[sub][r] * scale;
        if (diag && (sub * 16 + fr > wid * 16 + g * 4 + r)) v = -1e30f;
        p[sub][r] = v;
      }
    }
    float corr[4];
#pragma unroll
    for (int r = 0; r < 4; ++r) {
      float mx = fmaxf(fmaxf(p[0][r], p[1][r]), fmaxf(p[2][r], p[3][r]));
#pragma unroll
      for (int off = 1; off < 16; off <<= 1) mx = fmaxf(mx, __shfl_xor(mx, off));
      const float mn = fmaxf(m0[r], mx);
      corr[r] = __expf(m0[r] - mn);
      m0[r] = mn;
      float rs = 0.0f;
#pragma unroll
      for (int sub = 0; sub < 4; ++sub) { p[sub][r] = __expf(p[sub][r] - mn); rs += p[sub][r]; }
#pragma unroll
      for (int off = 1; off < 16; off <<= 1) rs += __shfl_xor(rs, off);
      l0[r] = l0[r] * corr[r] + rs;
    }
#pragma unroll
    for (int dt = 0; dt < 8; ++dt)
#pragma unroll
      for (int r = 0; r < 4; ++r) acc[dt][r] *= corr[r];

#pragma unroll
    for (int half = 0; half < 2; ++half) {
#pragma unroll
      for (int s2 = 0; s2 < 2; ++s2)
#pragma unroll
        for (int r = 0; r < 4; ++r)
          Pw[(g * 4 + r) * 40 + s2 * 16 + fr] = f2bf(p[half * 2 + s2][r]);
      bf16x8 pf = *(const bf16x8*)(&Pw[fr * 40 + g * 8]);
      __builtin_amdgcn_s_setprio(1);
#pragma unroll
      for (int dt = 0; dt < 8; ++dt) {
        const int row = dt * 16 + fr;
        bf16x8 vf = *(const bf16x8*)(&Vts[row * 64 + ((half * 32 + g * 8) ^ ((row & 7) << 3))]);
        acc[dt] = __builtin_amdgcn_mfma_f32_16x16x32_bf16(pf, vf, acc[dt], 0, 0, 0);
      }
      __builtin_amdgcn_s_setprio(0);
    }
  }

  float inv[4];
#pragma unroll
  for (int r = 0; r < 4; ++r) inv[r] = 1.0f / l0[r];
#pragma unroll
  for (int dt = 0; dt < 8; ++dt)
#pragma unroll
    for (int r = 0; r < 4; ++r) {
      const size_t row = (size_t)(b * S_ + qt * 64 + wid * 16 + g * 4 + r);
      outp[row * E_ + h * 128 + dt * 16 + fr] = f2bf(acc[dt][r] * inv[r]);
    }
}

// ---------------- launcher ----------------
extern "C" void kernel_launch(void* const* d_in, const int* in_sizes, int n_in,
                              void* d_out, int out_size, void* d_ws, size_t ws_size,
                              hipStream_t stream) {
  (void)in_sizes; (void)n_in; (void)out_size; (void)ws_size;
  const float* x    = (const float*)d_in[0];
  const float* ln1w = (const float*)d_in[1];
  const float* ln1b = (const float*)d_in[2];
  const float* Wqkv = (const float*)d_in[3];
  const float* Wo   = (const float*)d_in[4];
  const float* ln2w = (const float*)d_in[5];
  const float* ln2b = (const float*)d_in[6];
  const float* W1   = (const float*)d_in[7];
  const float* W2   = (const float*)d_in[8];
  float* out = (float*)d_out;
  char* ws = (char*)d_ws;

  // workspace layout (bytes)
  unsigned short* WqkvT = (unsigned short*)(ws + 0);            // 25,165,824
  unsigned short* WoT   = (unsigned short*)(ws + 25165824);     //  8,388,608
  unsigned short* W1T   = (unsigned short*)(ws + 33554432);     // 33,554,432
  unsigned short* W2T   = (unsigned short*)(ws + 67108864);     // 33,554,432
  unsigned short* qkvb  = (unsigned short*)(ws + 100663296);    // 50,331,648
  unsigned short* vTb   = (unsigned short*)(ws + 150994944);    // 16,777,216
  unsigned short* gbuf  = (unsigned short*)(ws + 100663296);    // 67,108,864 (reuses qkv+vT)
  unsigned short* hbuf  = (unsigned short*)(ws + 167772160);    // 16,777,216 (h / attnout / h2)
  float*          x1    = (float*)         (ws + 184549376);    // 33,554,432

  const dim3 tb(32, 8);
  hipLaunchKernelGGL(transpose_w, dim3(6144 / 32, 2048 / 32), tb, 0, stream, Wqkv, WqkvT, 2048, 6144);
  hipLaunchKernelGGL(transpose_w, dim3(2048 / 32, 2048 / 32), tb, 0, stream, Wo,   WoT,   2048, 2048);
  hipLaunchKernelGGL(transpose_w, dim3(8192 / 32, 2048 / 32), tb, 0, stream, W1,   W1T,   2048, 8192);
  hipLaunchKernelGGL(transpose_w, dim3(2048 / 32, 8192 / 32), tb, 0, stream, W2,   W2T,   8192, 2048);

  hipLaunchKernelGGL(ln_kernel, dim3(T_), dim3(256), 0, stream, x, ln1w, ln1b, hbuf);
  hipLaunchKernelGGL((gemm_bt<0>), dim3(32 * 48), dim3(256), 0, stream,
                     hbuf, WqkvT, (void*)qkvb, (const float*)nullptr, T_, 6144, 2048);
  hipLaunchKernelGGL(extract_vT, dim3(4, 64, 32), tb, 0, stream, qkvb, vTb);
  hipLaunchKernelGGL(attn_kernel, dim3(S_ / 64, B_ * H_), dim3(256), 0, stream, qkvb, vTb, hbuf);
  hipLaunchKernelGGL((gemm_bt<2>), dim3(32 * 16), dim3(256), 0, stream,
                     hbuf, WoT, (void*)x1, x, T_, 2048, 2048);
  hipLaunchKernelGGL(ln_kernel, dim3(T_), dim3(256), 0, stream, x1, ln2w, ln2b, hbuf);
  // A/B: W1 on the new asm 8-phase 256^2 kernel (512 blocks), W2 on known-good m97.
  hipLaunchKernelGGL((gemm256<1>), dim3(16 * 32), dim3(512), 0, stream,
                     hbuf, W1T, (void*)gbuf, (const float*)nullptr, T_, 8192, 2048);
  hipLaunchKernelGGL((gemm_bt<2>), dim3(32 * 16), dim3(256), 0, stream,
                     gbuf, W2T, (void*)out, x1, T_, 2048, 8192);
}